// Round 1
// 165.825 us; speedup vs baseline: 1.0163x; 1.0163x over previous
//
#include <hip/hip_runtime.h>
#include <stddef.h>

#define NN 2048
#define DIN 128
#define HD 32

typedef __attribute__((ext_vector_type(8))) short short8;
typedef __attribute__((ext_vector_type(4))) float f32x4;

constexpr float SLOPE = 0.2f;
constexpr float LC = 7.2134752044448170f; // log2(e)/TEMP

__device__ __forceinline__ unsigned int pack_rne(float a, float b){
    unsigned int xa = __float_as_uint(a), xb = __float_as_uint(b);
    unsigned int ra = (xa + 0x7fffu + ((xa >> 16) & 1u)) >> 16;
    unsigned int rb = (xb + 0x7fffu + ((xb >> 16) & 1u)) >> 16;
    return ra | (rb << 16);
}

__device__ __forceinline__ unsigned short bf16_rne(float a){
    unsigned int x = __float_as_uint(a);
    return (unsigned short)((x + 0x7fffu + ((x >> 16) & 1u)) >> 16);
}

// ---------------- kWh: Wh[bh][n][o] = sum_i h[b][n][i] * W[h][i][o] (f32) ---
__global__ __launch_bounds__(256) void kWh(const float* __restrict__ hg,
                                           const float* __restrict__ Wg,
                                           float* __restrict__ Wh)
{
    __shared__ float Wl[DIN*HD];
    __shared__ float Hl[8][DIN+4];   // +4 pad: bank = (4r+i)%32, conflict-free
    const int t = threadIdx.x;
    const int bh = blockIdx.x >> 5;
    const int tile = blockIdx.x & 31;
    const int b = bh >> 2, hh = bh & 3;
    for (int i = t; i < DIN*HD; i += 256) Wl[i] = Wg[hh*DIN*HD + i];
    const int o = t & 31, r = t >> 5;
    for (int it = 0; it < 8; ++it){
        const int nb = tile*64 + it*8;
        __syncthreads();
        {
            const float4 v = *(const float4*)&hg[((size_t)b*NN + nb + r)*DIN + o*4];
            *(float4*)&Hl[r][o*4] = v;
        }
        __syncthreads();
        float acc = 0.f;
        #pragma unroll 8
        for (int i = 0; i < DIN; ++i) acc = fmaf(Hl[r][i], Wl[i*HD+o], acc);
        Wh[((size_t)bh*NN + nb + r)*HD + o] = acc;
    }
}

// ---------------- kScore: s_src, s_dst, max partials, + WhT bf16 transpose --
// WhT[bh][o][n] bf16: the B-operand for kAttnM, converted ONCE here.
__global__ __launch_bounds__(256) void kScore(const float* __restrict__ Wh,
                                              const float* __restrict__ ag,
                                              float* __restrict__ sSrc,
                                              float* __restrict__ sDst,
                                              float* __restrict__ maxPart,
                                              unsigned short* __restrict__ WhT)
{
    __shared__ float al[64];
    __shared__ float wred[4];
    __shared__ unsigned short Tl[32][264];   // row pad to 264 keeps 16B align + spreads banks
    const int t = threadIdx.x;
    const int bh = blockIdx.x >> 3, seg = blockIdx.x & 7;
    const int hh = bh & 3;
    if (t < 64) al[t] = ag[hh*64 + t];
    __syncthreads();
    const int n = seg*256 + t;
    const float4* wr = (const float4*)&Wh[((size_t)bh*NN + n)*HD];
    float4 w[8];
    float ss = 0.f, sd = 0.f;
    #pragma unroll
    for (int q = 0; q < 8; ++q){
        w[q] = wr[q];
        ss += w[q].x*al[q*4+0] + w[q].y*al[q*4+1] + w[q].z*al[q*4+2] + w[q].w*al[q*4+3];
        sd += w[q].x*al[32+q*4+0] + w[q].y*al[32+q*4+1] + w[q].z*al[32+q*4+2] + w[q].w*al[32+q*4+3];
    }
    sSrc[bh*NN+n] = ss; sDst[bh*NN+n] = sd;
    // transpose row -> bf16 columns in LDS
    #pragma unroll
    for (int q = 0; q < 8; ++q){
        const float* f = (const float*)&w[q];
        #pragma unroll
        for (int k2 = 0; k2 < 4; ++k2)
            Tl[q*4+k2][t] = bf16_rne(f[k2]);
    }
    float lmax = sd;
    #pragma unroll
    for (int off = 32; off > 0; off >>= 1) lmax = fmaxf(lmax, __shfl_down(lmax, off));
    if ((t & 63) == 0) wred[t >> 6] = lmax;
    __syncthreads();
    // write WhT chunk [32 o-rows][256 n] — per inst: 8 lanes x 16B contiguous
    {
        const int o = t >> 3, ch = t & 7;
        const size_t base = ((size_t)bh*32 + o)*NN + seg*256;
        #pragma unroll
        for (int k = 0; k < 4; ++k)
            *(short8*)&WhT[base + k*64 + ch*8] = *(const short8*)&Tl[o][k*64 + ch*8];
    }
    if (t == 0) maxPart[bh*8 + seg] = fmaxf(fmaxf(wred[0], wred[1]), fmaxf(wred[2], wred[3]));
}

// ---------------- kAttnM: fused softmax (known max) + PV via MFMA -----------
// block = 4 waves x 16 rows = 64 rows; grid = 16 bh x 32 tiles.
// B-fragments read DIRECTLY from L2-resident WhT (bf16): no staging, no
// conversion, zero barriers in the main loop. sdl staged once per block.
__global__ __launch_bounds__(256) void kAttnM(const unsigned short* __restrict__ WhT,
                                              const float* __restrict__ sSrc,
                                              const float* __restrict__ sDst,
                                              const float* __restrict__ maxPart,
                                              float* __restrict__ invZ,
                                              unsigned short* __restrict__ hcb)
{
    __shared__ float sdl[NN];            // LC * s_dst for the whole bh (8 KB)
    const int t = threadIdx.x;
    const int lane = t & 63;
    const int wv = t >> 6;
    const int q = lane >> 4, c = lane & 15;
    const int bh = blockIdx.x >> 5;
    const int n0 = (blockIdx.x & 31)*64 + wv*16;
    const int b = bh >> 2, hh = bh & 3;
    for (int i = t; i < NN; i += 256) sdl[i] = LC * sDst[bh*NN + i];
    float mx = maxPart[bh*8];
    #pragma unroll
    for (int i = 1; i < 8; ++i) mx = fmaxf(mx, maxPart[bh*8 + i]);
    const float ssrc = sSrc[bh*NN + n0 + c];
    const float q0v = ssrc + mx;
    const float R = fmaxf(q0v, SLOPE*q0v) * LC;
    const float a1 = ssrc*LC - R;
    const float a2 = SLOPE*LC*ssrc - R;
    __syncthreads();
    const unsigned short* wb0 = WhT + (size_t)bh*32*NN + (size_t)c*NN + q*8;
    const unsigned short* wb1 = wb0 + (size_t)16*NN;
    f32x4 acc0 = {0.f,0.f,0.f,0.f}, acc1 = {0.f,0.f,0.f,0.f};
    float Zp = 0.f;
    short8 bF0 = *(const short8*)&wb0[0];
    short8 bF1 = *(const short8*)&wb1[0];
    #pragma unroll 4
    for (int it = 0; it < 64; ++it){
        const int m8 = it*32 + q*8;
        const int nx = ((it+1) & 63)*32;       // wraps to 0 on last iter (harmless)
        const short8 nF0 = *(const short8*)&wb0[nx];
        const short8 nF1 = *(const short8*)&wb1[nx];
        const f32x4 u0 = *(const f32x4*)&sdl[m8];
        const f32x4 u1 = *(const f32x4*)&sdl[m8+4];
        float p[8];
        #pragma unroll
        for (int j = 0; j < 4; ++j){
            p[j]   = exp2f(fmaxf(a1 + u0[j], fmaf(SLOPE, u0[j], a2)));
            p[4+j] = exp2f(fmaxf(a1 + u1[j], fmaf(SLOPE, u1[j], a2)));
        }
        short8 aF;
        #pragma unroll
        for (int j = 0; j < 8; j += 2){
            ((unsigned int*)&aF)[j>>1] = (__float_as_uint(p[j]) >> 16)
                                       | (__float_as_uint(p[j+1]) & 0xffff0000u);
            Zp += p[j] + p[j+1];
        }
        acc0 = __builtin_amdgcn_mfma_f32_16x16x32_bf16(aF, bF0, acc0, 0, 0, 0);
        acc1 = __builtin_amdgcn_mfma_f32_16x16x32_bf16(aF, bF1, acc1, 0, 0, 0);
        bF0 = nF0; bF1 = nF1;
    }
    Zp += __shfl_xor(Zp, 16);
    Zp += __shfl_xor(Zp, 32);
    const float iz = 1.0f / Zp;
    if (q == 0) invZ[bh*NN + n0 + c] = iz;
    #pragma unroll
    for (int reg = 0; reg < 4; ++reg){
        const int row = q*4 + reg;
        const float izr = __shfl(iz, row);
        const size_t base = ((size_t)b*NN + n0 + row)*128 + hh*32;
        hcb[base + c]      = (unsigned short)((pack_rne(acc0[reg]*izr, 0.f)) & 0xffffu);
        hcb[base + 16 + c] = (unsigned short)((pack_rne(acc1[reg]*izr, 0.f)) & 0xffffu);
    }
}

// ---------------- kAlpha: alpha.mean over heads -> out1 (f32) ---------------
__global__ __launch_bounds__(256) void kAlpha(const float* __restrict__ sSrc,
                                              const float* __restrict__ sDst,
                                              const float* __restrict__ maxPart,
                                              const float* __restrict__ invZ,
                                              float* __restrict__ out1)
{
    __shared__ float sdl[4][NN];     // LC * s_dst, 32 KB
    const int t = threadIdx.x;
    const int b = blockIdx.x >> 9;
    const int n0 = (blockIdx.x & 511) * 4;
    for (int i = t; i < 4*NN; i += 256)
        sdl[i >> 11][i & (NN-1)] = LC * sDst[(size_t)(b*4 + (i>>11))*NN + (i & (NN-1))];
    __syncthreads();
    float a1[4][4], a2[4][4], cf[4][4];   // [row][head]
    #pragma unroll
    for (int hh = 0; hh < 4; ++hh){
        float mx = maxPart[(b*4+hh)*8];
        #pragma unroll
        for (int i = 1; i < 8; ++i) mx = fmaxf(mx, maxPart[(b*4+hh)*8 + i]);
        #pragma unroll
        for (int rr = 0; rr < 4; ++rr){
            const int bhn = (b*4+hh)*NN + n0 + rr;
            const float ss = sSrc[bhn];
            const float q0 = ss + mx;
            const float R = fmaxf(q0, SLOPE*q0)*LC;
            a1[rr][hh] = ss*LC - R;
            a2[rr][hh] = SLOPE*LC*ss - R;
            cf[rr][hh] = 0.25f * invZ[bhn];
        }
    }
    for (int mb = 0; mb < NN; mb += 256){
        const int m = mb + t;
        const float u0 = sdl[0][m], u1 = sdl[1][m], u2 = sdl[2][m], u3 = sdl[3][m];
        #pragma unroll
        for (int rr = 0; rr < 4; ++rr){
            float v;
            v  = cf[rr][0]*exp2f(fmaxf(a1[rr][0]+u0, fmaf(SLOPE, u0, a2[rr][0])));
            v += cf[rr][1]*exp2f(fmaxf(a1[rr][1]+u1, fmaf(SLOPE, u1, a2[rr][1])));
            v += cf[rr][2]*exp2f(fmaxf(a1[rr][2]+u2, fmaf(SLOPE, u2, a2[rr][2])));
            v += cf[rr][3]*exp2f(fmaxf(a1[rr][3]+u3, fmaf(SLOPE, u3, a2[rr][3])));
            out1[((size_t)b*NN + n0 + rr)*NN + m] = v;
        }
    }
}

// ---------------- kMergeM: out0 = hcb(bf16) @ mw^T(bf16) + bias via MFMA ----
__global__ __launch_bounds__(256) void kMergeM(const unsigned short* __restrict__ hcb,
                                               const float* __restrict__ mw,
                                               const float* __restrict__ mbv,
                                               float* __restrict__ out0)
{
    __shared__ unsigned short mwb[128][136];
    const int t = threadIdx.x;
    const int wv = t >> 6, lane = t & 63;
    const int q = lane >> 4, c = lane & 15;
    for (int i = t; i < 128*64; i += 256){
        const int j = i >> 6, k2 = i & 63;
        const float2 v = *(const float2*)&mw[j*128 + k2*2];
        *(unsigned int*)&mwb[j][k2*2] = pack_rne(v.x, v.y);
    }
    __syncthreads();
    const int row0 = blockIdx.x*64 + wv*16;
    f32x4 acc[8];
    #pragma unroll
    for (int ot = 0; ot < 8; ++ot) acc[ot] = (f32x4){0.f,0.f,0.f,0.f};
    #pragma unroll
    for (int ks = 0; ks < 4; ++ks){
        const short8 aF = *(const short8*)&hcb[((size_t)row0 + c)*128 + ks*32 + q*8];
        #pragma unroll
        for (int ot = 0; ot < 8; ++ot){
            const short8 bF = *(const short8*)&mwb[ot*16 + c][ks*32 + q*8];
            acc[ot] = __builtin_amdgcn_mfma_f32_16x16x32_bf16(aF, bF, acc[ot], 0, 0, 0);
        }
    }
    #pragma unroll
    for (int ot = 0; ot < 8; ++ot){
        const int col = ot*16 + c;
        const float bias = mbv[col];
        #pragma unroll
        for (int reg = 0; reg < 4; ++reg){
            const size_t row = (size_t)row0 + q*4 + reg;
            out0[row*128 + col] = acc[ot][reg] + bias;
        }
    }
}

extern "C" void kernel_launch(void* const* d_in, const int* in_sizes, int n_in,
                              void* d_out, int out_size, void* d_ws, size_t ws_size,
                              hipStream_t stream)
{
    const float* hg  = (const float*)d_in[0];
    const float* Wg  = (const float*)d_in[1];
    const float* ag  = (const float*)d_in[2];
    const float* mw  = (const float*)d_in[3];
    const float* mbv = (const float*)d_in[4];
    float* out0 = (float*)d_out;
    float* out1 = out0 + (size_t)4*NN*128;

    float* ws     = (float*)d_ws;
    float* Wh     = ws;                       // 1,048,576 f32
    float* sSrc   = Wh + 1048576;             //    32,768
    float* sDst   = sSrc + 32768;             //    32,768
    float* maxPart= sDst + 32768;             //       128
    float* invZ   = maxPart + 128;            //    32,768
    unsigned short* hcb = (unsigned short*)(invZ + 32768);  // 1,048,576 bf16
    unsigned short* WhT = hcb + 1048576;      // 1,048,576 bf16 [bh][32][2048]

    hipLaunchKernelGGL(kWh,    dim3(512),  dim3(256), 0, stream, hg, Wg, Wh);
    hipLaunchKernelGGL(kScore, dim3(128),  dim3(256), 0, stream, Wh, ag, sSrc, sDst, maxPart, WhT);
    hipLaunchKernelGGL(kAttnM, dim3(512),  dim3(256), 0, stream, WhT, sSrc, sDst, maxPart, invZ, hcb);
    hipLaunchKernelGGL(kAlpha, dim3(2048), dim3(256), 0, stream, sSrc, sDst, maxPart, invZ, out1);
    hipLaunchKernelGGL(kMergeM,dim3(128),  dim3(256), 0, stream, hcb, mw, mbv, out0);
}

// Round 2
// 143.232 us; speedup vs baseline: 1.1766x; 1.1577x over previous
//
#include <hip/hip_runtime.h>
#include <stddef.h>

#define NN 2048
#define DIN 128
#define HD 32

typedef __attribute__((ext_vector_type(8))) short short8;
typedef __attribute__((ext_vector_type(4))) float f32x4;
typedef __attribute__((ext_vector_type(4))) unsigned short us4;

constexpr float SLOPE = 0.2f;
constexpr float LC = 7.2134752044448170f; // log2(e)/TEMP

__device__ __forceinline__ unsigned int pack_rne(float a, float b){
    unsigned int xa = __float_as_uint(a), xb = __float_as_uint(b);
    unsigned int ra = (xa + 0x7fffu + ((xa >> 16) & 1u)) >> 16;
    unsigned int rb = (xb + 0x7fffu + ((xb >> 16) & 1u)) >> 16;
    return ra | (rb << 16);
}

__device__ __forceinline__ unsigned short bf16_rne(float a){
    unsigned int x = __float_as_uint(a);
    return (unsigned short)((x + 0x7fffu + ((x >> 16) & 1u)) >> 16);
}

// raw v_exp_f32: args here are <= 0 (max-subtracted); sub-denormal output
// differences are < 2^-126 and irrelevant at this tolerance.
__device__ __forceinline__ float fexp2(float x){
    float r; asm("v_exp_f32 %0, %1" : "=v"(r) : "v"(x)); return r;
}

// ---------------- kPrep: W -> Bt hi/lo bf16 [col=h*32+o][i]; mw -> bf16 ----
__global__ __launch_bounds__(256) void kPrep(const float* __restrict__ Wg,
                                             const float* __restrict__ mw,
                                             unsigned short* __restrict__ BtHi,
                                             unsigned short* __restrict__ BtLo,
                                             unsigned short* __restrict__ mwB)
{
    const int t = threadIdx.x;
    if (blockIdx.x < 16){
        const int col = blockIdx.x*8 + (t>>5);
        const int i0  = (t&31)*4;
        const int h = col >> 5, o = col & 31;
        us4 vh, vl;
        #pragma unroll
        for (int j = 0; j < 4; ++j){
            const float w = Wg[(h*DIN + i0 + j)*HD + o];
            const unsigned short hi = bf16_rne(w);
            const float hf = __uint_as_float((unsigned int)hi << 16);
            vh[j] = hi;
            vl[j] = bf16_rne(w - hf);
        }
        *(us4*)&BtHi[col*DIN + i0] = vh;
        *(us4*)&BtLo[col*DIN + i0] = vl;
    } else {
        const int col = (blockIdx.x - 16)*8 + (t>>5);
        const int k0  = (t&31)*4;
        const f32x4 v = *(const f32x4*)&mw[col*128 + k0];
        us4 p;
        #pragma unroll
        for (int j = 0; j < 4; ++j) p[j] = bf16_rne(v[j]);
        *(us4*)&mwB[col*128 + k0] = p;
    }
}

// ---------------- kWh: split-bf16 MFMA GEMM + fused score/max/WhT ----------
// grid 512 x 256thr. Block = 16 rows (all 128 cols); wave w = head w.
// Wh never hits memory: epilogue emits WhT bf16, sSrc/sDst (f32 via shfl
// reduce of acc frags), and per-16-row s_dst max partials.
__global__ __launch_bounds__(256) void kWh(const float* __restrict__ hg,
                                           const unsigned short* __restrict__ BtHi,
                                           const unsigned short* __restrict__ BtLo,
                                           const float* __restrict__ ag,
                                           unsigned short* __restrict__ WhT,
                                           float* __restrict__ sSrc,
                                           float* __restrict__ sDst,
                                           float* __restrict__ maxPartW)
{
    __shared__ float Hl[16][DIN+4];
    const int t = threadIdx.x;
    const int wv = t >> 6, lane = t & 63;
    const int q = lane >> 4, c = lane & 15;
    const int r0 = blockIdx.x * 16;
    const int b  = r0 >> 11;
    const int n0 = r0 & (NN-1);
    {
        const int r = t >> 5, c4 = t & 31;
        *(float4*)&Hl[r][c4*4] = *(const float4*)&hg[((size_t)b*NN + n0 + r)*DIN + c4*4];
        const int f2 = t + 256, r2 = f2 >> 5, c42 = f2 & 31;
        *(float4*)&Hl[r2][c42*4] = *(const float4*)&hg[((size_t)b*NN + n0 + r2)*DIN + c42*4];
    }
    __syncthreads();
    // A fragments hi/lo: row c, k = ks*32 + q*8 + j
    short8 Ahi[4], Alo[4];
    #pragma unroll
    for (int k = 0; k < 4; ++k){
        const float* sp = &Hl[c][k*32 + q*8];
        #pragma unroll
        for (int j2 = 0; j2 < 2; ++j2){
            const f32x4 x = *(const f32x4*)&sp[j2*4];
            #pragma unroll
            for (int j = 0; j < 4; ++j){
                const unsigned short hi = bf16_rne(x[j]);
                const float hf = __uint_as_float((unsigned int)hi << 16);
                ((unsigned short*)&Ahi[k])[j2*4+j] = hi;
                ((unsigned short*)&Alo[k])[j2*4+j] = bf16_rne(x[j] - hf);
            }
        }
    }
    const int hh = wv;
    const int bh = b*4 + hh;
    f32x4 acc0 = {0.f,0.f,0.f,0.f}, acc1 = {0.f,0.f,0.f,0.f};
    #pragma unroll
    for (int k = 0; k < 4; ++k){
        const int koff = k*32 + q*8;
        const short8 Bh0 = *(const short8*)&BtHi[(hh*32      + c)*DIN + koff];
        const short8 Bl0 = *(const short8*)&BtLo[(hh*32      + c)*DIN + koff];
        const short8 Bh1 = *(const short8*)&BtHi[(hh*32 + 16 + c)*DIN + koff];
        const short8 Bl1 = *(const short8*)&BtLo[(hh*32 + 16 + c)*DIN + koff];
        acc0 = __builtin_amdgcn_mfma_f32_16x16x32_bf16(Ahi[k], Bh0, acc0, 0, 0, 0);
        acc1 = __builtin_amdgcn_mfma_f32_16x16x32_bf16(Ahi[k], Bh1, acc1, 0, 0, 0);
        acc0 = __builtin_amdgcn_mfma_f32_16x16x32_bf16(Ahi[k], Bl0, acc0, 0, 0, 0);
        acc1 = __builtin_amdgcn_mfma_f32_16x16x32_bf16(Ahi[k], Bl1, acc1, 0, 0, 0);
        acc0 = __builtin_amdgcn_mfma_f32_16x16x32_bf16(Alo[k], Bh0, acc0, 0, 0, 0);
        acc1 = __builtin_amdgcn_mfma_f32_16x16x32_bf16(Alo[k], Bh1, acc1, 0, 0, 0);
    }
    // WhT[bh][o][n] bf16 (C/D layout: col=lane&15, row=q*4+reg)
    {
        us4 w0, w1;
        #pragma unroll
        for (int reg = 0; reg < 4; ++reg){
            w0[reg] = bf16_rne(acc0[reg]);
            w1[reg] = bf16_rne(acc1[reg]);
        }
        *(us4*)&WhT[((size_t)bh*32      + c)*NN + n0 + q*4] = w0;
        *(us4*)&WhT[((size_t)bh*32 + 16 + c)*NN + n0 + q*4] = w1;
    }
    // scores: s[row] = sum_o Wh[row][o] * a[o]   (reduce over c lanes)
    const float aS0 = ag[hh*64 + c],      aS1 = ag[hh*64 + 16 + c];
    const float aD0 = ag[hh*64 + 32 + c], aD1 = ag[hh*64 + 48 + c];
    float vs[4], vd[4];
    #pragma unroll
    for (int reg = 0; reg < 4; ++reg){
        vs[reg] = acc0[reg]*aS0 + acc1[reg]*aS1;
        vd[reg] = acc0[reg]*aD0 + acc1[reg]*aD1;
    }
    #pragma unroll
    for (int m = 1; m <= 8; m <<= 1){
        #pragma unroll
        for (int reg = 0; reg < 4; ++reg){
            vs[reg] += __shfl_xor(vs[reg], m);
            vd[reg] += __shfl_xor(vd[reg], m);
        }
    }
    if (c == 0){
        *(f32x4*)&sSrc[(size_t)bh*NN + n0 + q*4] = (f32x4){vs[0],vs[1],vs[2],vs[3]};
        *(f32x4*)&sDst[(size_t)bh*NN + n0 + q*4] = (f32x4){vd[0],vd[1],vd[2],vd[3]};
    }
    float wm = fmaxf(fmaxf(vd[0],vd[1]), fmaxf(vd[2],vd[3]));
    wm = fmaxf(wm, __shfl_xor(wm, 16));
    wm = fmaxf(wm, __shfl_xor(wm, 32));
    if (lane == 0) maxPartW[bh*128 + (n0 >> 4)] = wm;
}

// ---------------- kAttnM: fused softmax (known max) + PV via MFMA -----------
__global__ __launch_bounds__(256) void kAttnM(const unsigned short* __restrict__ WhT,
                                              const float* __restrict__ sSrc,
                                              const float* __restrict__ sDst,
                                              const float* __restrict__ maxPartW,
                                              float* __restrict__ invZ,
                                              unsigned short* __restrict__ hcb)
{
    __shared__ float sdl[NN];            // LC * s_dst for the whole bh (8 KB)
    __shared__ float smax[4];
    const int t = threadIdx.x;
    const int lane = t & 63;
    const int wv = t >> 6;
    const int q = lane >> 4, c = lane & 15;
    const int bh = blockIdx.x >> 5;
    const int n0 = (blockIdx.x & 31)*64 + wv*16;
    const int b = bh >> 2, hh = bh & 3;
    for (int i = t; i < NN; i += 256) sdl[i] = LC * sDst[bh*NN + i];
    {
        float v = maxPartW[bh*128 + ((wv&1)<<6) + lane];
        #pragma unroll
        for (int off = 32; off; off >>= 1) v = fmaxf(v, __shfl_xor(v, off));
        if (lane == 0) smax[wv] = v;
    }
    const float ssrc = sSrc[bh*NN + n0 + c];
    __syncthreads();
    const float mx = fmaxf(fmaxf(smax[0], smax[1]), fmaxf(smax[2], smax[3]));
    const float q0v = ssrc + mx;
    const float R = fmaxf(q0v, SLOPE*q0v) * LC;
    const float a1 = ssrc*LC - R;
    const float a2 = SLOPE*LC*ssrc - R;
    const unsigned short* wb0 = WhT + (size_t)bh*32*NN + (size_t)c*NN + q*8;
    const unsigned short* wb1 = wb0 + (size_t)16*NN;
    f32x4 acc0 = {0.f,0.f,0.f,0.f}, acc1 = {0.f,0.f,0.f,0.f};
    float Zp = 0.f;
    short8 bF0 = *(const short8*)&wb0[0];
    short8 bF1 = *(const short8*)&wb1[0];
    #pragma unroll 4
    for (int it = 0; it < 64; ++it){
        const int m8 = it*32 + q*8;
        const int nx = ((it+1) & 63)*32;       // wraps to 0 on last iter (harmless)
        const short8 nF0 = *(const short8*)&wb0[nx];
        const short8 nF1 = *(const short8*)&wb1[nx];
        const f32x4 u0 = *(const f32x4*)&sdl[m8];
        const f32x4 u1 = *(const f32x4*)&sdl[m8+4];
        float p[8];
        #pragma unroll
        for (int j = 0; j < 4; ++j){
            p[j]   = fexp2(fmaxf(a1 + u0[j], fmaf(SLOPE, u0[j], a2)));
            p[4+j] = fexp2(fmaxf(a1 + u1[j], fmaf(SLOPE, u1[j], a2)));
        }
        short8 aF;
        #pragma unroll
        for (int j = 0; j < 8; j += 2){
            ((unsigned int*)&aF)[j>>1] = (__float_as_uint(p[j]) >> 16)
                                       | (__float_as_uint(p[j+1]) & 0xffff0000u);
            Zp += p[j] + p[j+1];
        }
        acc0 = __builtin_amdgcn_mfma_f32_16x16x32_bf16(aF, bF0, acc0, 0, 0, 0);
        acc1 = __builtin_amdgcn_mfma_f32_16x16x32_bf16(aF, bF1, acc1, 0, 0, 0);
        bF0 = nF0; bF1 = nF1;
    }
    Zp += __shfl_xor(Zp, 16);
    Zp += __shfl_xor(Zp, 32);
    const float iz = 1.0f / Zp;
    if (q == 0) invZ[bh*NN + n0 + c] = iz;
    #pragma unroll
    for (int reg = 0; reg < 4; ++reg){
        const int row = q*4 + reg;
        const float izr = __shfl(iz, row);
        const size_t base = ((size_t)b*NN + n0 + row)*128 + hh*32;
        hcb[base + c]      = (unsigned short)((pack_rne(acc0[reg]*izr, 0.f)) & 0xffffu);
        hcb[base + 16 + c] = (unsigned short)((pack_rne(acc1[reg]*izr, 0.f)) & 0xffffu);
    }
}

// ---------------- kAlpha: alpha.mean over heads -> out1 (f32) ---------------
__global__ __launch_bounds__(256) void kAlpha(const float* __restrict__ sSrc,
                                              const float* __restrict__ sDst,
                                              const float* __restrict__ maxPartW,
                                              const float* __restrict__ invZ,
                                              float* __restrict__ out1)
{
    __shared__ float sdl[4][NN];     // LC * s_dst, 32 KB
    __shared__ float mxl[4];
    const int t = threadIdx.x;
    const int wv = t >> 6, lane = t & 63;
    const int b = blockIdx.x >> 9;
    const int n0 = (blockIdx.x & 511) * 4;
    {   // wave w reduces head w's 128 max partials
        float v = fmaxf(maxPartW[(b*4+wv)*128 + lane], maxPartW[(b*4+wv)*128 + 64 + lane]);
        #pragma unroll
        for (int off = 32; off; off >>= 1) v = fmaxf(v, __shfl_xor(v, off));
        if (lane == 0) mxl[wv] = v;
    }
    for (int i = t; i < 4*NN; i += 256)
        sdl[i >> 11][i & (NN-1)] = LC * sDst[(size_t)(b*4 + (i>>11))*NN + (i & (NN-1))];
    __syncthreads();
    float a1[4][4], a2[4][4], cf[4][4];   // [row][head]
    #pragma unroll
    for (int hh = 0; hh < 4; ++hh){
        const float mx = mxl[hh];
        #pragma unroll
        for (int rr = 0; rr < 4; ++rr){
            const int bhn = (b*4+hh)*NN + n0 + rr;
            const float ss = sSrc[bhn];
            const float q0 = ss + mx;
            const float R = fmaxf(q0, SLOPE*q0)*LC;
            a1[rr][hh] = ss*LC - R;
            a2[rr][hh] = SLOPE*LC*ss - R;
            cf[rr][hh] = 0.25f * invZ[bhn];
        }
    }
    for (int mb = 0; mb < NN; mb += 256){
        const int m = mb + t;
        const float u0 = sdl[0][m], u1 = sdl[1][m], u2 = sdl[2][m], u3 = sdl[3][m];
        #pragma unroll
        for (int rr = 0; rr < 4; ++rr){
            float v;
            v  = cf[rr][0]*fexp2(fmaxf(a1[rr][0]+u0, fmaf(SLOPE, u0, a2[rr][0])));
            v += cf[rr][1]*fexp2(fmaxf(a1[rr][1]+u1, fmaf(SLOPE, u1, a2[rr][1])));
            v += cf[rr][2]*fexp2(fmaxf(a1[rr][2]+u2, fmaf(SLOPE, u2, a2[rr][2])));
            v += cf[rr][3]*fexp2(fmaxf(a1[rr][3]+u3, fmaf(SLOPE, u3, a2[rr][3])));
            out1[((size_t)b*NN + n0 + rr)*NN + m] = v;
        }
    }
}

// ---------------- kMergeM: out0 = hcb(bf16) @ mwB^T + bias via MFMA ---------
// No LDS staging: B-frags straight from L2-hot mwB. grid 256, 32 rows/block.
__global__ __launch_bounds__(256) void kMergeM(const unsigned short* __restrict__ hcb,
                                               const unsigned short* __restrict__ mwB,
                                               const float* __restrict__ mbv,
                                               float* __restrict__ out0)
{
    const int t = threadIdx.x;
    const int wv = t >> 6, lane = t & 63;
    const int q = lane >> 4, c = lane & 15;
    const int r0 = blockIdx.x*32 + (wv&1)*16;
    const int ch = (wv>>1)*64;
    f32x4 acc[4];
    #pragma unroll
    for (int ot = 0; ot < 4; ++ot) acc[ot] = (f32x4){0.f,0.f,0.f,0.f};
    #pragma unroll
    for (int ks = 0; ks < 4; ++ks){
        const short8 aF = *(const short8*)&hcb[((size_t)r0 + c)*128 + ks*32 + q*8];
        #pragma unroll
        for (int ot = 0; ot < 4; ++ot){
            const short8 bF = *(const short8*)&mwB[(size_t)(ch + ot*16 + c)*128 + ks*32 + q*8];
            acc[ot] = __builtin_amdgcn_mfma_f32_16x16x32_bf16(aF, bF, acc[ot], 0, 0, 0);
        }
    }
    #pragma unroll
    for (int ot = 0; ot < 4; ++ot){
        const int col = ch + ot*16 + c;
        const float bias = mbv[col];
        #pragma unroll
        for (int reg = 0; reg < 4; ++reg){
            const size_t row = (size_t)r0 + q*4 + reg;
            out0[row*128 + col] = acc[ot][reg] + bias;
        }
    }
}

extern "C" void kernel_launch(void* const* d_in, const int* in_sizes, int n_in,
                              void* d_out, int out_size, void* d_ws, size_t ws_size,
                              hipStream_t stream)
{
    const float* hg  = (const float*)d_in[0];
    const float* Wg  = (const float*)d_in[1];
    const float* ag  = (const float*)d_in[2];
    const float* mw  = (const float*)d_in[3];
    const float* mbv = (const float*)d_in[4];
    float* out0 = (float*)d_out;
    float* out1 = out0 + (size_t)4*NN*128;

    float* ws      = (float*)d_ws;
    float* sSrc    = ws;                       //    32,768 f32
    float* sDst    = sSrc + 32768;             //    32,768
    float* maxPartW= sDst + 32768;             //     2,048
    float* invZ    = maxPartW + 2048;          //    32,768
    unsigned short* hcb  = (unsigned short*)(invZ + 32768);   // 1,048,576 bf16
    unsigned short* WhT  = hcb + 1048576;      // 1,048,576 bf16 [bh][32][2048]
    unsigned short* BtHi = WhT + 1048576;      //    16,384 bf16
    unsigned short* BtLo = BtHi + 16384;       //    16,384
    unsigned short* mwB  = BtLo + 16384;       //    16,384

    hipLaunchKernelGGL(kPrep,  dim3(32),   dim3(256), 0, stream, Wg, mw, BtHi, BtLo, mwB);
    hipLaunchKernelGGL(kWh,    dim3(512),  dim3(256), 0, stream, hg, BtHi, BtLo, ag, WhT, sSrc, sDst, maxPartW);
    hipLaunchKernelGGL(kAttnM, dim3(512),  dim3(256), 0, stream, WhT, sSrc, sDst, maxPartW, invZ, hcb);
    hipLaunchKernelGGL(kAlpha, dim3(2048), dim3(256), 0, stream, sSrc, sDst, maxPartW, invZ, out1);
    hipLaunchKernelGGL(kMergeM,dim3(256),  dim3(256), 0, stream, hcb, mwB, mbv, out0);
}

// Round 4
// 141.476 us; speedup vs baseline: 1.1912x; 1.0124x over previous
//
#include <hip/hip_runtime.h>
#include <stddef.h>

#define NN 2048
#define DIN 128
#define HD 32

typedef __attribute__((ext_vector_type(8))) short short8;
typedef __attribute__((ext_vector_type(4))) float f32x4;
typedef __attribute__((ext_vector_type(4))) unsigned short us4;

constexpr float SLOPE = 0.2f;
constexpr float LC = 7.2134752044448170f; // log2(e)/TEMP

__device__ __forceinline__ unsigned int pack_rne(float a, float b){
    unsigned int xa = __float_as_uint(a), xb = __float_as_uint(b);
    unsigned int ra = (xa + 0x7fffu + ((xa >> 16) & 1u)) >> 16;
    unsigned int rb = (xb + 0x7fffu + ((xb >> 16) & 1u)) >> 16;
    return ra | (rb << 16);
}

__device__ __forceinline__ unsigned short bf16_rne(float a){
    unsigned int x = __float_as_uint(a);
    return (unsigned short)((x + 0x7fffu + ((x >> 16) & 1u)) >> 16);
}

// raw v_exp_f32: args here are <= 0 (max-subtracted); sub-denormal output
// differences are < 2^-126 and irrelevant at this tolerance.
__device__ __forceinline__ float fexp2(float x){
    float r; asm("v_exp_f32 %0, %1" : "=v"(r) : "v"(x)); return r;
}

// ---------------- kPrep: W -> Bt hi/lo bf16 [col=h*32+o][i]; mw -> bf16 ----
__global__ __launch_bounds__(256) void kPrep(const float* __restrict__ Wg,
                                             const float* __restrict__ mw,
                                             unsigned short* __restrict__ BtHi,
                                             unsigned short* __restrict__ BtLo,
                                             unsigned short* __restrict__ mwB)
{
    const int t = threadIdx.x;
    if (blockIdx.x < 16){
        const int col = blockIdx.x*8 + (t>>5);
        const int i0  = (t&31)*4;
        const int h = col >> 5, o = col & 31;
        us4 vh, vl;
        #pragma unroll
        for (int j = 0; j < 4; ++j){
            const float w = Wg[(h*DIN + i0 + j)*HD + o];
            const unsigned short hi = bf16_rne(w);
            const float hf = __uint_as_float((unsigned int)hi << 16);
            vh[j] = hi;
            vl[j] = bf16_rne(w - hf);
        }
        *(us4*)&BtHi[col*DIN + i0] = vh;
        *(us4*)&BtLo[col*DIN + i0] = vl;
    } else {
        const int col = (blockIdx.x - 16)*8 + (t>>5);
        const int k0  = (t&31)*4;
        const f32x4 v = *(const f32x4*)&mw[col*128 + k0];
        us4 p;
        #pragma unroll
        for (int j = 0; j < 4; ++j) p[j] = bf16_rne(v[j]);
        *(us4*)&mwB[col*128 + k0] = p;
    }
}

// ---------------- kWh: split-bf16 MFMA GEMM + fused score/max/WhT ----------
// (bit-exact round-2 version: scalar bf16_rne hi/lo split)
__global__ __launch_bounds__(256) void kWh(const float* __restrict__ hg,
                                           const unsigned short* __restrict__ BtHi,
                                           const unsigned short* __restrict__ BtLo,
                                           const float* __restrict__ ag,
                                           unsigned short* __restrict__ WhT,
                                           float* __restrict__ sSrc,
                                           float* __restrict__ sDst,
                                           float* __restrict__ maxPartW)
{
    __shared__ float Hl[16][DIN+4];
    const int t = threadIdx.x;
    const int wv = t >> 6, lane = t & 63;
    const int q = lane >> 4, c = lane & 15;
    const int r0 = blockIdx.x * 16;
    const int b  = r0 >> 11;
    const int n0 = r0 & (NN-1);
    {
        const int r = t >> 5, c4 = t & 31;
        *(float4*)&Hl[r][c4*4] = *(const float4*)&hg[((size_t)b*NN + n0 + r)*DIN + c4*4];
        const int f2 = t + 256, r2 = f2 >> 5, c42 = f2 & 31;
        *(float4*)&Hl[r2][c42*4] = *(const float4*)&hg[((size_t)b*NN + n0 + r2)*DIN + c42*4];
    }
    __syncthreads();
    // A fragments hi/lo
    short8 Ahi[4], Alo[4];
    #pragma unroll
    for (int k = 0; k < 4; ++k){
        const float* sp = &Hl[c][k*32 + q*8];
        #pragma unroll
        for (int j2 = 0; j2 < 2; ++j2){
            const f32x4 x = *(const f32x4*)&sp[j2*4];
            #pragma unroll
            for (int j = 0; j < 4; ++j){
                const unsigned short hi = bf16_rne(x[j]);
                const float hf = __uint_as_float((unsigned int)hi << 16);
                ((unsigned short*)&Ahi[k])[j2*4+j] = hi;
                ((unsigned short*)&Alo[k])[j2*4+j] = bf16_rne(x[j] - hf);
            }
        }
    }
    const int hh = wv;
    const int bh = b*4 + hh;
    f32x4 acc0 = {0.f,0.f,0.f,0.f}, acc1 = {0.f,0.f,0.f,0.f};
    #pragma unroll
    for (int k = 0; k < 4; ++k){
        const int koff = k*32 + q*8;
        const short8 Bh0 = *(const short8*)&BtHi[(hh*32      + c)*DIN + koff];
        const short8 Bl0 = *(const short8*)&BtLo[(hh*32      + c)*DIN + koff];
        const short8 Bh1 = *(const short8*)&BtHi[(hh*32 + 16 + c)*DIN + koff];
        const short8 Bl1 = *(const short8*)&BtLo[(hh*32 + 16 + c)*DIN + koff];
        acc0 = __builtin_amdgcn_mfma_f32_16x16x32_bf16(Ahi[k], Bh0, acc0, 0, 0, 0);
        acc1 = __builtin_amdgcn_mfma_f32_16x16x32_bf16(Ahi[k], Bh1, acc1, 0, 0, 0);
        acc0 = __builtin_amdgcn_mfma_f32_16x16x32_bf16(Ahi[k], Bl0, acc0, 0, 0, 0);
        acc1 = __builtin_amdgcn_mfma_f32_16x16x32_bf16(Ahi[k], Bl1, acc1, 0, 0, 0);
        acc0 = __builtin_amdgcn_mfma_f32_16x16x32_bf16(Alo[k], Bh0, acc0, 0, 0, 0);
        acc1 = __builtin_amdgcn_mfma_f32_16x16x32_bf16(Alo[k], Bh1, acc1, 0, 0, 0);
    }
    // WhT[bh][o][n] bf16 (C/D layout: col=lane&15, row=q*4+reg)
    {
        us4 w0, w1;
        #pragma unroll
        for (int reg = 0; reg < 4; ++reg){
            w0[reg] = bf16_rne(acc0[reg]);
            w1[reg] = bf16_rne(acc1[reg]);
        }
        *(us4*)&WhT[((size_t)bh*32      + c)*NN + n0 + q*4] = w0;
        *(us4*)&WhT[((size_t)bh*32 + 16 + c)*NN + n0 + q*4] = w1;
    }
    const float aS0 = ag[hh*64 + c],      aS1 = ag[hh*64 + 16 + c];
    const float aD0 = ag[hh*64 + 32 + c], aD1 = ag[hh*64 + 48 + c];
    float vs[4], vd[4];
    #pragma unroll
    for (int reg = 0; reg < 4; ++reg){
        vs[reg] = acc0[reg]*aS0 + acc1[reg]*aS1;
        vd[reg] = acc0[reg]*aD0 + acc1[reg]*aD1;
    }
    #pragma unroll
    for (int m = 1; m <= 8; m <<= 1){
        #pragma unroll
        for (int reg = 0; reg < 4; ++reg){
            vs[reg] += __shfl_xor(vs[reg], m);
            vd[reg] += __shfl_xor(vd[reg], m);
        }
    }
    if (c == 0){
        *(f32x4*)&sSrc[(size_t)bh*NN + n0 + q*4] = (f32x4){vs[0],vs[1],vs[2],vs[3]};
        *(f32x4*)&sDst[(size_t)bh*NN + n0 + q*4] = (f32x4){vd[0],vd[1],vd[2],vd[3]};
    }
    float wm = fmaxf(fmaxf(vd[0],vd[1]), fmaxf(vd[2],vd[3]));
    wm = fmaxf(wm, __shfl_xor(wm, 16));
    wm = fmaxf(wm, __shfl_xor(wm, 32));
    if (lane == 0) maxPartW[bh*128 + (n0 >> 4)] = wm;
}

// ---------------- kAttnM: fused softmax (known max) + PV via MFMA -----------
// (bit-exact round-2 version: grid 512, full-m per wave, scalar Zp)
__global__ __launch_bounds__(256) void kAttnM(const unsigned short* __restrict__ WhT,
                                              const float* __restrict__ sSrc,
                                              const float* __restrict__ sDst,
                                              const float* __restrict__ maxPartW,
                                              float* __restrict__ invZ,
                                              unsigned short* __restrict__ hcb)
{
    __shared__ float sdl[NN];            // LC * s_dst for the whole bh (8 KB)
    __shared__ float smax[4];
    const int t = threadIdx.x;
    const int lane = t & 63;
    const int wv = t >> 6;
    const int q = lane >> 4, c = lane & 15;
    const int bh = blockIdx.x >> 5;
    const int n0 = (blockIdx.x & 31)*64 + wv*16;
    const int b = bh >> 2, hh = bh & 3;
    for (int i = t; i < NN; i += 256) sdl[i] = LC * sDst[bh*NN + i];
    {
        float v = maxPartW[bh*128 + ((wv&1)<<6) + lane];
        #pragma unroll
        for (int off = 32; off; off >>= 1) v = fmaxf(v, __shfl_xor(v, off));
        if (lane == 0) smax[wv] = v;
    }
    const float ssrc = sSrc[bh*NN + n0 + c];
    __syncthreads();
    const float mx = fmaxf(fmaxf(smax[0], smax[1]), fmaxf(smax[2], smax[3]));
    const float q0v = ssrc + mx;
    const float R = fmaxf(q0v, SLOPE*q0v) * LC;
    const float a1 = ssrc*LC - R;
    const float a2 = SLOPE*LC*ssrc - R;
    const unsigned short* wb0 = WhT + (size_t)bh*32*NN + (size_t)c*NN + q*8;
    const unsigned short* wb1 = wb0 + (size_t)16*NN;
    f32x4 acc0 = {0.f,0.f,0.f,0.f}, acc1 = {0.f,0.f,0.f,0.f};
    float Zp = 0.f;
    short8 bF0 = *(const short8*)&wb0[0];
    short8 bF1 = *(const short8*)&wb1[0];
    #pragma unroll 4
    for (int it = 0; it < 64; ++it){
        const int m8 = it*32 + q*8;
        const int nx = ((it+1) & 63)*32;       // wraps to 0 on last iter (harmless)
        const short8 nF0 = *(const short8*)&wb0[nx];
        const short8 nF1 = *(const short8*)&wb1[nx];
        const f32x4 u0 = *(const f32x4*)&sdl[m8];
        const f32x4 u1 = *(const f32x4*)&sdl[m8+4];
        float p[8];
        #pragma unroll
        for (int j = 0; j < 4; ++j){
            p[j]   = fexp2(fmaxf(a1 + u0[j], fmaf(SLOPE, u0[j], a2)));
            p[4+j] = fexp2(fmaxf(a1 + u1[j], fmaf(SLOPE, u1[j], a2)));
        }
        short8 aF;
        #pragma unroll
        for (int j = 0; j < 8; j += 2){
            ((unsigned int*)&aF)[j>>1] = (__float_as_uint(p[j]) >> 16)
                                       | (__float_as_uint(p[j+1]) & 0xffff0000u);
            Zp += p[j] + p[j+1];
        }
        acc0 = __builtin_amdgcn_mfma_f32_16x16x32_bf16(aF, bF0, acc0, 0, 0, 0);
        acc1 = __builtin_amdgcn_mfma_f32_16x16x32_bf16(aF, bF1, acc1, 0, 0, 0);
        bF0 = nF0; bF1 = nF1;
    }
    Zp += __shfl_xor(Zp, 16);
    Zp += __shfl_xor(Zp, 32);
    const float iz = 1.0f / Zp;
    if (q == 0) invZ[bh*NN + n0 + c] = iz;
    #pragma unroll
    for (int reg = 0; reg < 4; ++reg){
        const int row = q*4 + reg;
        const float izr = __shfl(iz, row);
        const size_t base = ((size_t)b*NN + n0 + row)*128 + hh*32;
        hcb[base + c]      = (unsigned short)((pack_rne(acc0[reg]*izr, 0.f)) & 0xffffu);
        hcb[base + 16 + c] = (unsigned short)((pack_rne(acc1[reg]*izr, 0.f)) & 0xffffu);
    }
}

// ---------------- kTail: merge (blocks 0..255) || alpha (blocks 256..2303) --
// Bodies are bit-exact round-2 kMergeM / kAlpha; only fused into one launch.
__global__ __launch_bounds__(256) void kTail(const float* __restrict__ sSrc,
                                             const float* __restrict__ sDst,
                                             const float* __restrict__ maxPartW,
                                             const float* __restrict__ invZ,
                                             const unsigned short* __restrict__ hcb,
                                             const unsigned short* __restrict__ mwB,
                                             const float* __restrict__ mbv,
                                             float* __restrict__ out0,
                                             float* __restrict__ out1)
{
    __shared__ float sdl[4][NN];     // alpha only (32 KB)
    __shared__ float mxl[4];
    const int t = threadIdx.x;
    const int wv = t >> 6, lane = t & 63;
    if (blockIdx.x < 256){
        // ---- merge: out0 = hcb(bf16) @ mwB^T + bias via MFMA ----
        const int q = lane >> 4, c = lane & 15;
        const int r0 = blockIdx.x*32 + (wv&1)*16;
        const int ch = (wv>>1)*64;
        f32x4 acc[4];
        #pragma unroll
        for (int ot = 0; ot < 4; ++ot) acc[ot] = (f32x4){0.f,0.f,0.f,0.f};
        #pragma unroll
        for (int ks = 0; ks < 4; ++ks){
            const short8 aF = *(const short8*)&hcb[((size_t)r0 + c)*128 + ks*32 + q*8];
            #pragma unroll
            for (int ot = 0; ot < 4; ++ot){
                const short8 bF = *(const short8*)&mwB[(size_t)(ch + ot*16 + c)*128 + ks*32 + q*8];
                acc[ot] = __builtin_amdgcn_mfma_f32_16x16x32_bf16(aF, bF, acc[ot], 0, 0, 0);
            }
        }
        #pragma unroll
        for (int ot = 0; ot < 4; ++ot){
            const int col = ch + ot*16 + c;
            const float bias = mbv[col];
            #pragma unroll
            for (int reg = 0; reg < 4; ++reg){
                const size_t row = (size_t)r0 + q*4 + reg;
                out0[row*128 + col] = acc[ot][reg] + bias;
            }
        }
        return;
    }
    // ---- alpha: out1[b][n][m] = 0.25 * sum_h alpha_h ----
    const int bidA = blockIdx.x - 256;
    const int b = bidA >> 9;
    const int n0 = (bidA & 511) * 4;
    {   // wave w reduces head w's 128 max partials
        float v = fmaxf(maxPartW[(b*4+wv)*128 + lane], maxPartW[(b*4+wv)*128 + 64 + lane]);
        #pragma unroll
        for (int off = 32; off; off >>= 1) v = fmaxf(v, __shfl_xor(v, off));
        if (lane == 0) mxl[wv] = v;
    }
    for (int i = t; i < 4*NN; i += 256)
        sdl[i >> 11][i & (NN-1)] = LC * sDst[(size_t)(b*4 + (i>>11))*NN + (i & (NN-1))];
    __syncthreads();
    float a1[4][4], a2[4][4], cf[4][4];   // [row][head]
    #pragma unroll
    for (int hh = 0; hh < 4; ++hh){
        const float mx = mxl[hh];
        #pragma unroll
        for (int rr = 0; rr < 4; ++rr){
            const int bhn = (b*4+hh)*NN + n0 + rr;
            const float ss = sSrc[bhn];
            const float q0 = ss + mx;
            const float R = fmaxf(q0, SLOPE*q0)*LC;
            a1[rr][hh] = ss*LC - R;
            a2[rr][hh] = SLOPE*LC*ss - R;
            cf[rr][hh] = 0.25f * invZ[bhn];
        }
    }
    for (int mb = 0; mb < NN; mb += 256){
        const int m = mb + t;
        const float u0 = sdl[0][m], u1 = sdl[1][m], u2 = sdl[2][m], u3 = sdl[3][m];
        #pragma unroll
        for (int rr = 0; rr < 4; ++rr){
            float v;
            v  = cf[rr][0]*fexp2(fmaxf(a1[rr][0]+u0, fmaf(SLOPE, u0, a2[rr][0])));
            v += cf[rr][1]*fexp2(fmaxf(a1[rr][1]+u1, fmaf(SLOPE, u1, a2[rr][1])));
            v += cf[rr][2]*fexp2(fmaxf(a1[rr][2]+u2, fmaf(SLOPE, u2, a2[rr][2])));
            v += cf[rr][3]*fexp2(fmaxf(a1[rr][3]+u3, fmaf(SLOPE, u3, a2[rr][3])));
            __builtin_nontemporal_store(v, &out1[((size_t)b*NN + n0 + rr)*NN + m]);
        }
    }
}

extern "C" void kernel_launch(void* const* d_in, const int* in_sizes, int n_in,
                              void* d_out, int out_size, void* d_ws, size_t ws_size,
                              hipStream_t stream)
{
    const float* hg  = (const float*)d_in[0];
    const float* Wg  = (const float*)d_in[1];
    const float* ag  = (const float*)d_in[2];
    const float* mw  = (const float*)d_in[3];
    const float* mbv = (const float*)d_in[4];
    float* out0 = (float*)d_out;
    float* out1 = out0 + (size_t)4*NN*128;

    float* ws      = (float*)d_ws;
    float* sSrc    = ws;                       //    32,768 f32
    float* sDst    = sSrc + 32768;             //    32,768
    float* maxPartW= sDst + 32768;             //     2,048
    float* invZ    = maxPartW + 2048;          //    32,768
    unsigned short* hcb  = (unsigned short*)(invZ + 32768);   // 1,048,576 bf16
    unsigned short* WhT  = hcb + 1048576;      // 1,048,576 bf16 [bh][32][2048]
    unsigned short* BtHi = WhT + 1048576;      //    16,384 bf16
    unsigned short* BtLo = BtHi + 16384;       //    16,384
    unsigned short* mwB  = BtLo + 16384;       //    16,384

    hipLaunchKernelGGL(kPrep,  dim3(32),   dim3(256), 0, stream, Wg, mw, BtHi, BtLo, mwB);
    hipLaunchKernelGGL(kWh,    dim3(512),  dim3(256), 0, stream, hg, BtHi, BtLo, ag, WhT, sSrc, sDst, maxPartW);
    hipLaunchKernelGGL(kAttnM, dim3(512),  dim3(256), 0, stream, WhT, sSrc, sDst, maxPartW, invZ, hcb);
    hipLaunchKernelGGL(kTail,  dim3(2304), dim3(256), 0, stream, sSrc, sDst, maxPartW, invZ, hcb, mwB, mbv, out0, out1);
}

// Round 5
// 140.015 us; speedup vs baseline: 1.2036x; 1.0104x over previous
//
#include <hip/hip_runtime.h>
#include <stddef.h>

#define NN 2048
#define DIN 128
#define HD 32

typedef __attribute__((ext_vector_type(8))) short short8;
typedef __attribute__((ext_vector_type(4))) float f32x4;
typedef __attribute__((ext_vector_type(4))) unsigned short us4;

constexpr float SLOPE = 0.2f;
constexpr float LC = 7.2134752044448170f; // log2(e)/TEMP

__device__ __forceinline__ unsigned int pack_rne(float a, float b){
    unsigned int xa = __float_as_uint(a), xb = __float_as_uint(b);
    unsigned int ra = (xa + 0x7fffu + ((xa >> 16) & 1u)) >> 16;
    unsigned int rb = (xb + 0x7fffu + ((xb >> 16) & 1u)) >> 16;
    return ra | (rb << 16);
}

__device__ __forceinline__ unsigned short bf16_rne(float a){
    unsigned int x = __float_as_uint(a);
    return (unsigned short)((x + 0x7fffu + ((x >> 16) & 1u)) >> 16);
}

// raw v_exp_f32: args here are <= 0 (max-subtracted); sub-denormal output
// differences are < 2^-126 and irrelevant at this tolerance.
__device__ __forceinline__ float fexp2(float x){
    float r; asm("v_exp_f32 %0, %1" : "=v"(r) : "v"(x)); return r;
}

// ---------------- kPrep: W -> Bt hi/lo bf16 [col=h*32+o][i]; mw -> bf16 ----
__global__ __launch_bounds__(256) void kPrep(const float* __restrict__ Wg,
                                             const float* __restrict__ mw,
                                             unsigned short* __restrict__ BtHi,
                                             unsigned short* __restrict__ BtLo,
                                             unsigned short* __restrict__ mwB)
{
    const int t = threadIdx.x;
    if (blockIdx.x < 16){
        const int col = blockIdx.x*8 + (t>>5);
        const int i0  = (t&31)*4;
        const int h = col >> 5, o = col & 31;
        us4 vh, vl;
        #pragma unroll
        for (int j = 0; j < 4; ++j){
            const float w = Wg[(h*DIN + i0 + j)*HD + o];
            const unsigned short hi = bf16_rne(w);
            const float hf = __uint_as_float((unsigned int)hi << 16);
            vh[j] = hi;
            vl[j] = bf16_rne(w - hf);
        }
        *(us4*)&BtHi[col*DIN + i0] = vh;
        *(us4*)&BtLo[col*DIN + i0] = vl;
    } else {
        const int col = (blockIdx.x - 16)*8 + (t>>5);
        const int k0  = (t&31)*4;
        const f32x4 v = *(const f32x4*)&mw[col*128 + k0];
        us4 p;
        #pragma unroll
        for (int j = 0; j < 4; ++j) p[j] = bf16_rne(v[j]);
        *(us4*)&mwB[col*128 + k0] = p;
    }
}

// ---------------- kWh: split-bf16 MFMA GEMM + fused score/max/WhT ----------
// (bit-exact round-4 version)
__global__ __launch_bounds__(256) void kWh(const float* __restrict__ hg,
                                           const unsigned short* __restrict__ BtHi,
                                           const unsigned short* __restrict__ BtLo,
                                           const float* __restrict__ ag,
                                           unsigned short* __restrict__ WhT,
                                           float* __restrict__ sSrc,
                                           float* __restrict__ sDst,
                                           float* __restrict__ maxPartW)
{
    __shared__ float Hl[16][DIN+4];
    const int t = threadIdx.x;
    const int wv = t >> 6, lane = t & 63;
    const int q = lane >> 4, c = lane & 15;
    const int r0 = blockIdx.x * 16;
    const int b  = r0 >> 11;
    const int n0 = r0 & (NN-1);
    {
        const int r = t >> 5, c4 = t & 31;
        *(float4*)&Hl[r][c4*4] = *(const float4*)&hg[((size_t)b*NN + n0 + r)*DIN + c4*4];
        const int f2 = t + 256, r2 = f2 >> 5, c42 = f2 & 31;
        *(float4*)&Hl[r2][c42*4] = *(const float4*)&hg[((size_t)b*NN + n0 + r2)*DIN + c42*4];
    }
    __syncthreads();
    // A fragments hi/lo
    short8 Ahi[4], Alo[4];
    #pragma unroll
    for (int k = 0; k < 4; ++k){
        const float* sp = &Hl[c][k*32 + q*8];
        #pragma unroll
        for (int j2 = 0; j2 < 2; ++j2){
            const f32x4 x = *(const f32x4*)&sp[j2*4];
            #pragma unroll
            for (int j = 0; j < 4; ++j){
                const unsigned short hi = bf16_rne(x[j]);
                const float hf = __uint_as_float((unsigned int)hi << 16);
                ((unsigned short*)&Ahi[k])[j2*4+j] = hi;
                ((unsigned short*)&Alo[k])[j2*4+j] = bf16_rne(x[j] - hf);
            }
        }
    }
    const int hh = wv;
    const int bh = b*4 + hh;
    f32x4 acc0 = {0.f,0.f,0.f,0.f}, acc1 = {0.f,0.f,0.f,0.f};
    #pragma unroll
    for (int k = 0; k < 4; ++k){
        const int koff = k*32 + q*8;
        const short8 Bh0 = *(const short8*)&BtHi[(hh*32      + c)*DIN + koff];
        const short8 Bl0 = *(const short8*)&BtLo[(hh*32      + c)*DIN + koff];
        const short8 Bh1 = *(const short8*)&BtHi[(hh*32 + 16 + c)*DIN + koff];
        const short8 Bl1 = *(const short8*)&BtLo[(hh*32 + 16 + c)*DIN + koff];
        acc0 = __builtin_amdgcn_mfma_f32_16x16x32_bf16(Ahi[k], Bh0, acc0, 0, 0, 0);
        acc1 = __builtin_amdgcn_mfma_f32_16x16x32_bf16(Ahi[k], Bh1, acc1, 0, 0, 0);
        acc0 = __builtin_amdgcn_mfma_f32_16x16x32_bf16(Ahi[k], Bl0, acc0, 0, 0, 0);
        acc1 = __builtin_amdgcn_mfma_f32_16x16x32_bf16(Ahi[k], Bl1, acc1, 0, 0, 0);
        acc0 = __builtin_amdgcn_mfma_f32_16x16x32_bf16(Alo[k], Bh0, acc0, 0, 0, 0);
        acc1 = __builtin_amdgcn_mfma_f32_16x16x32_bf16(Alo[k], Bh1, acc1, 0, 0, 0);
    }
    // WhT[bh][o][n] bf16 (C/D layout: col=lane&15, row=q*4+reg)
    {
        us4 w0, w1;
        #pragma unroll
        for (int reg = 0; reg < 4; ++reg){
            w0[reg] = bf16_rne(acc0[reg]);
            w1[reg] = bf16_rne(acc1[reg]);
        }
        *(us4*)&WhT[((size_t)bh*32      + c)*NN + n0 + q*4] = w0;
        *(us4*)&WhT[((size_t)bh*32 + 16 + c)*NN + n0 + q*4] = w1;
    }
    const float aS0 = ag[hh*64 + c],      aS1 = ag[hh*64 + 16 + c];
    const float aD0 = ag[hh*64 + 32 + c], aD1 = ag[hh*64 + 48 + c];
    float vs[4], vd[4];
    #pragma unroll
    for (int reg = 0; reg < 4; ++reg){
        vs[reg] = acc0[reg]*aS0 + acc1[reg]*aS1;
        vd[reg] = acc0[reg]*aD0 + acc1[reg]*aD1;
    }
    #pragma unroll
    for (int m = 1; m <= 8; m <<= 1){
        #pragma unroll
        for (int reg = 0; reg < 4; ++reg){
            vs[reg] += __shfl_xor(vs[reg], m);
            vd[reg] += __shfl_xor(vd[reg], m);
        }
    }
    if (c == 0){
        *(f32x4*)&sSrc[(size_t)bh*NN + n0 + q*4] = (f32x4){vs[0],vs[1],vs[2],vs[3]};
        *(f32x4*)&sDst[(size_t)bh*NN + n0 + q*4] = (f32x4){vd[0],vd[1],vd[2],vd[3]};
    }
    float wm = fmaxf(fmaxf(vd[0],vd[1]), fmaxf(vd[2],vd[3]));
    wm = fmaxf(wm, __shfl_xor(wm, 16));
    wm = fmaxf(wm, __shfl_xor(wm, 32));
    if (lane == 0) maxPartW[bh*128 + (n0 >> 4)] = wm;
}

// ---------------- kAttnM: softmax + PV, m-halves split across wave pairs ----
// grid = 16 bh x 64 tiles (32 rows each). Wave wv: rg=wv>>1 (row-group of 16),
// mh=wv&1 (m-half of 1024). 4096 waves = 4/SIMD. Zp path identical to the
// proven round-4 code (scalar accumulate + q-butterfly); the only new piece
// is the LDS pair-reduction of {acc0, acc1, Zf}.
__global__ __launch_bounds__(256) void kAttnM(const unsigned short* __restrict__ WhT,
                                              const float* __restrict__ sSrc,
                                              const float* __restrict__ sDst,
                                              const float* __restrict__ maxPartW,
                                              float* __restrict__ invZ,
                                              unsigned short* __restrict__ hcb)
{
    __shared__ float sdl[NN];            // LC * s_dst for the whole bh (8 KB)
    __shared__ float smax[4];
    __shared__ float red[2][64][9];      // stride 9 (odd): 2 lanes/bank = free
    const int t = threadIdx.x;
    const int lane = t & 63;
    const int wv = t >> 6;
    const int q = lane >> 4, c = lane & 15;
    const int bh = blockIdx.x >> 6;
    const int tile = blockIdx.x & 63;
    const int rg = wv >> 1, mh = wv & 1;
    const int n0 = tile*32 + rg*16;
    const int b = bh >> 2, hh = bh & 3;
    for (int i = t; i < NN; i += 256) sdl[i] = LC * sDst[bh*NN + i];
    {
        float v = maxPartW[bh*128 + (mh<<6) + lane];
        #pragma unroll
        for (int off = 32; off; off >>= 1) v = fmaxf(v, __shfl_xor(v, off));
        if (lane == 0) smax[wv] = v;
    }
    const float ssrc = sSrc[bh*NN + n0 + c];
    __syncthreads();
    const float mx = fmaxf(fmaxf(smax[0], smax[1]), fmaxf(smax[2], smax[3]));
    const float q0v = ssrc + mx;
    const float R = fmaxf(q0v, SLOPE*q0v) * LC;
    const float a1 = ssrc*LC - R;
    const float a2 = SLOPE*LC*ssrc - R;
    const unsigned short* wb0 = WhT + (size_t)bh*32*NN + (size_t)c*NN + mh*1024 + q*8;
    const unsigned short* wb1 = wb0 + (size_t)16*NN;
    const float* sdb = &sdl[mh*1024];
    f32x4 acc0 = {0.f,0.f,0.f,0.f}, acc1 = {0.f,0.f,0.f,0.f};
    float Zp = 0.f;
    short8 bF0 = *(const short8*)&wb0[0];
    short8 bF1 = *(const short8*)&wb1[0];
    #pragma unroll 4
    for (int it = 0; it < 32; ++it){
        const int m8 = it*32 + q*8;
        const int nx = ((it+1) & 31)*32;       // wraps to 0 on last iter (harmless)
        const short8 nF0 = *(const short8*)&wb0[nx];
        const short8 nF1 = *(const short8*)&wb1[nx];
        const f32x4 u0 = *(const f32x4*)&sdb[m8];
        const f32x4 u1 = *(const f32x4*)&sdb[m8+4];
        float p[8];
        #pragma unroll
        for (int j = 0; j < 4; ++j){
            p[j]   = fexp2(fmaxf(a1 + u0[j], fmaf(SLOPE, u0[j], a2)));
            p[4+j] = fexp2(fmaxf(a1 + u1[j], fmaf(SLOPE, u1[j], a2)));
        }
        short8 aF;
        #pragma unroll
        for (int j = 0; j < 8; j += 2){
            ((unsigned int*)&aF)[j>>1] = (__float_as_uint(p[j]) >> 16)
                                       | (__float_as_uint(p[j+1]) & 0xffff0000u);
            Zp += p[j] + p[j+1];
        }
        acc0 = __builtin_amdgcn_mfma_f32_16x16x32_bf16(aF, bF0, acc0, 0, 0, 0);
        acc1 = __builtin_amdgcn_mfma_f32_16x16x32_bf16(aF, bF1, acc1, 0, 0, 0);
        bF0 = nF0; bF1 = nF1;
    }
    // per-wave: combine q-slices -> Zf valid per lane for row c (half-m sum)
    Zp += __shfl_xor(Zp, 16);
    Zp += __shfl_xor(Zp, 32);
    // pair-reduce across m-halves through LDS
    if (mh == 1){
        #pragma unroll
        for (int k2 = 0; k2 < 4; ++k2){
            red[rg][lane][k2]     = acc0[k2];
            red[rg][lane][4 + k2] = acc1[k2];
        }
        red[rg][lane][8] = Zp;
    }
    __syncthreads();
    if (mh == 0){
        #pragma unroll
        for (int k2 = 0; k2 < 4; ++k2){
            acc0[k2] += red[rg][lane][k2];
            acc1[k2] += red[rg][lane][4 + k2];
        }
        Zp += red[rg][lane][8];
        const float iz = 1.0f / Zp;          // Z for row n0 + c
        if (q == 0) invZ[bh*NN + n0 + c] = iz;
        #pragma unroll
        for (int reg = 0; reg < 4; ++reg){
            const int row = q*4 + reg;
            const float izr = __shfl(iz, row);
            const size_t base = ((size_t)b*NN + n0 + row)*128 + hh*32;
            hcb[base + c]      = (unsigned short)((pack_rne(acc0[reg]*izr, 0.f)) & 0xffffu);
            hcb[base + 16 + c] = (unsigned short)((pack_rne(acc1[reg]*izr, 0.f)) & 0xffffu);
        }
    }
}

// ---------------- kTail: merge (blocks 0..255) || alpha (blocks 256..2303) --
__global__ __launch_bounds__(256) void kTail(const float* __restrict__ sSrc,
                                             const float* __restrict__ sDst,
                                             const float* __restrict__ maxPartW,
                                             const float* __restrict__ invZ,
                                             const unsigned short* __restrict__ hcb,
                                             const unsigned short* __restrict__ mwB,
                                             const float* __restrict__ mbv,
                                             float* __restrict__ out0,
                                             float* __restrict__ out1)
{
    __shared__ float sdl[4][NN];     // alpha only (32 KB)
    __shared__ float mxl[4];
    const int t = threadIdx.x;
    const int wv = t >> 6, lane = t & 63;
    if (blockIdx.x < 256){
        // ---- merge: out0 = hcb(bf16) @ mwB^T + bias via MFMA ----
        const int q = lane >> 4, c = lane & 15;
        const int r0 = blockIdx.x*32 + (wv&1)*16;
        const int ch = (wv>>1)*64;
        f32x4 acc[4];
        #pragma unroll
        for (int ot = 0; ot < 4; ++ot) acc[ot] = (f32x4){0.f,0.f,0.f,0.f};
        #pragma unroll
        for (int ks = 0; ks < 4; ++ks){
            const short8 aF = *(const short8*)&hcb[((size_t)r0 + c)*128 + ks*32 + q*8];
            #pragma unroll
            for (int ot = 0; ot < 4; ++ot){
                const short8 bF = *(const short8*)&mwB[(size_t)(ch + ot*16 + c)*128 + ks*32 + q*8];
                acc[ot] = __builtin_amdgcn_mfma_f32_16x16x32_bf16(aF, bF, acc[ot], 0, 0, 0);
            }
        }
        #pragma unroll
        for (int ot = 0; ot < 4; ++ot){
            const int col = ch + ot*16 + c;
            const float bias = mbv[col];
            #pragma unroll
            for (int reg = 0; reg < 4; ++reg){
                const size_t row = (size_t)r0 + q*4 + reg;
                out0[row*128 + col] = acc[ot][reg] + bias;
            }
        }
        return;
    }
    // ---- alpha: out1[b][n][m] = 0.25 * sum_h alpha_h ----
    const int bidA = blockIdx.x - 256;
    const int b = bidA >> 9;
    const int n0 = (bidA & 511) * 4;
    {   // wave w reduces head w's 128 max partials
        float v = fmaxf(maxPartW[(b*4+wv)*128 + lane], maxPartW[(b*4+wv)*128 + 64 + lane]);
        #pragma unroll
        for (int off = 32; off; off >>= 1) v = fmaxf(v, __shfl_xor(v, off));
        if (lane == 0) mxl[wv] = v;
    }
    for (int i = t; i < 4*NN; i += 256)
        sdl[i >> 11][i & (NN-1)] = LC * sDst[(size_t)(b*4 + (i>>11))*NN + (i & (NN-1))];
    __syncthreads();
    float a1[4][4], a2[4][4], cf[4][4];   // [row][head]
    #pragma unroll
    for (int hh = 0; hh < 4; ++hh){
        const float mx = mxl[hh];
        #pragma unroll
        for (int rr = 0; rr < 4; ++rr){
            const int bhn = (b*4+hh)*NN + n0 + rr;
            const float ss = sSrc[bhn];
            const float q0 = ss + mx;
            const float R = fmaxf(q0, SLOPE*q0)*LC;
            a1[rr][hh] = ss*LC - R;
            a2[rr][hh] = SLOPE*LC*ss - R;
            cf[rr][hh] = 0.25f * invZ[bhn];
        }
    }
    for (int mb = 0; mb < NN; mb += 256){
        const int m = mb + t;
        const float u0 = sdl[0][m], u1 = sdl[1][m], u2 = sdl[2][m], u3 = sdl[3][m];
        #pragma unroll
        for (int rr = 0; rr < 4; ++rr){
            float v;
            v  = cf[rr][0]*fexp2(fmaxf(a1[rr][0]+u0, fmaf(SLOPE, u0, a2[rr][0])));
            v += cf[rr][1]*fexp2(fmaxf(a1[rr][1]+u1, fmaf(SLOPE, u1, a2[rr][1])));
            v += cf[rr][2]*fexp2(fmaxf(a1[rr][2]+u2, fmaf(SLOPE, u2, a2[rr][2])));
            v += cf[rr][3]*fexp2(fmaxf(a1[rr][3]+u3, fmaf(SLOPE, u3, a2[rr][3])));
            __builtin_nontemporal_store(v, &out1[((size_t)b*NN + n0 + rr)*NN + m]);
        }
    }
}

extern "C" void kernel_launch(void* const* d_in, const int* in_sizes, int n_in,
                              void* d_out, int out_size, void* d_ws, size_t ws_size,
                              hipStream_t stream)
{
    const float* hg  = (const float*)d_in[0];
    const float* Wg  = (const float*)d_in[1];
    const float* ag  = (const float*)d_in[2];
    const float* mw  = (const float*)d_in[3];
    const float* mbv = (const float*)d_in[4];
    float* out0 = (float*)d_out;
    float* out1 = out0 + (size_t)4*NN*128;

    float* ws      = (float*)d_ws;
    float* sSrc    = ws;                       //    32,768 f32
    float* sDst    = sSrc + 32768;             //    32,768
    float* maxPartW= sDst + 32768;             //     2,048
    float* invZ    = maxPartW + 2048;          //    32,768
    unsigned short* hcb  = (unsigned short*)(invZ + 32768);   // 1,048,576 bf16
    unsigned short* WhT  = hcb + 1048576;      // 1,048,576 bf16 [bh][32][2048]
    unsigned short* BtHi = WhT + 1048576;      //    16,384 bf16
    unsigned short* BtLo = BtHi + 16384;       //    16,384
    unsigned short* mwB  = BtLo + 16384;       //    16,384

    hipLaunchKernelGGL(kPrep,  dim3(32),   dim3(256), 0, stream, Wg, mw, BtHi, BtLo, mwB);
    hipLaunchKernelGGL(kWh,    dim3(512),  dim3(256), 0, stream, hg, BtHi, BtLo, ag, WhT, sSrc, sDst, maxPartW);
    hipLaunchKernelGGL(kAttnM, dim3(1024), dim3(256), 0, stream, WhT, sSrc, sDst, maxPartW, invZ, hcb);
    hipLaunchKernelGGL(kTail,  dim3(2304), dim3(256), 0, stream, sSrc, sDst, maxPartW, invZ, hcb, mwB, mbv, out0, out1);
}